// Round 15
// baseline (54.660 us; speedup 1.0000x reference)
//
#include <hip/hip_runtime.h>

typedef __attribute__((ext_vector_type(8))) short bf16x8;
typedef __attribute__((ext_vector_type(8))) unsigned short ushort8;
typedef __attribute__((ext_vector_type(4))) float f32x4;

static __device__ __forceinline__ unsigned short f2bf(float f) {
  union { float f; unsigned u; } v; v.f = f;
  unsigned r = v.u + 0x7FFFu + ((v.u >> 16) & 1u);
  return (unsigned short)(r >> 16);
}
static __device__ __forceinline__ int iclamp(int x, int lo, int hi) {
  return x < lo ? lo : (x > hi ? hi : x);
}
// async global->LDS, 16B per lane; LDS dest = wave-uniform base + lane*16
static __device__ __forceinline__ void gl_lds16(const unsigned short* g,
                                                unsigned short* l) {
  __builtin_amdgcn_global_load_lds(
      (const __attribute__((address_space(1))) void*)g,
      (__attribute__((address_space(3))) void*)l, 16, 0, 0);
}

// ---------------- fused fp32 -> bf16 converts (one launch) ----------------
__global__ void cvt_all(const float* __restrict__ x,
                        const float* __restrict__ w_in,
                        const float* __restrict__ w_out,
                        unsigned short* __restrict__ xb,
                        unsigned short* __restrict__ wbin,
                        unsigned short* __restrict__ wbo) {
  const int NX4 = 1048576, NWI4 = 196608, NWO4 = 65536;  // float4 counts
  const int total = NX4 + NWI4 + NWO4;
  for (int i = blockIdx.x * blockDim.x + threadIdx.x; i < total;
       i += gridDim.x * blockDim.x) {
    const float* src;
    unsigned short* dst;
    int o;
    if (i < NX4) {
      src = x; dst = xb; o = i;
    } else if (i < NX4 + NWI4) {
      src = w_in; dst = wbin; o = i - NX4;
    } else {
      src = w_out; dst = wbo; o = i - NX4 - NWI4;
    }
    float4 v = reinterpret_cast<const float4*>(src)[o];
    ushort4 u;
    u.x = f2bf(v.x); u.y = f2bf(v.y); u.z = f2bf(v.z); u.w = f2bf(v.w);
    reinterpret_cast<ushort4*>(dst)[o] = u;
  }
}

// ------- GEMM: C[M][N] = A[M][K](bf16) * B[N][K](bf16)^T + bias -------
// (r14: 2-phase dbuf, gl_lds w16 pre-swizzled source, post-MFMA drain,
//  BK template; OUT_BF16: vectorized epilogue via C-restage)
template <int BM, int BN, int WM, int WN, int BK, int OUT_BF16>
__global__ __launch_bounds__(256) void gemm_bt(
    const unsigned short* __restrict__ A, const unsigned short* __restrict__ B,
    const float* __restrict__ bias, void* __restrict__ Cv,
    int M, int N, int K) {
  __shared__ unsigned short As[2][BM][BK];
  __shared__ unsigned short Bs[2][BN][BK];
  const int tid = threadIdx.x;
  const int lane = tid & 63;
  const int wid = tid >> 6;

  const int nwg = gridDim.x * gridDim.y;
  const int orig = blockIdx.y * gridDim.x + blockIdx.x;
  const int q = nwg >> 3, r = nwg & 7;
  const int xcd = orig & 7, lid = orig >> 3;
  const int swz = (xcd < r ? xcd * (q + 1) : r * (q + 1) + (xcd - r) * q) + lid;
  const int bm = (swz / gridDim.x) * BM;
  const int bn = (swz % gridDim.x) * BN;

  const int NWC = BN / WN;
  const int wr = (wid / NWC) * WM;
  const int wc = (wid % NWC) * WN;
  const int row16 = lane & 15;
  const int kgrp = lane >> 4;
  const int rsw = (BK == 64) ? (row16 & 7) : (row16 & 3);

  const int RPI = 1024 / (BK * 2);  // rows per gl_lds instr: 8 or 16
  const int lrow = (BK == 64) ? (lane >> 3) : (lane >> 2);
  const int lch = (BK == 64) ? ((lane & 7) ^ (lane >> 3))
                             : ((lane & 3) ^ ((lane >> 2) & 3));
  const int srA = wid * (BM / 4) + lrow;
  const int srB = wid * (BN / 4) + lrow;
  const unsigned short* gA = A + (size_t)(bm + srA) * K + lch * 8;
  const unsigned short* gB = B + (size_t)(bn + srB) * K + lch * 8;
  const size_t KR = (size_t)RPI * K;

#define STAGE(buf, k0)                                                     \
  {                                                                        \
    _Pragma("unroll") for (int j = 0; j < BM / (4 * RPI); ++j)             \
        gl_lds16(gA + j * KR + (k0),                                       \
                 &As[buf][wid * (BM / 4) + j * RPI][0]);                   \
    _Pragma("unroll") for (int j = 0; j < BN / (4 * RPI); ++j)             \
        gl_lds16(gB + j * KR + (k0),                                       \
                 &Bs[buf][wid * (BN / 4) + j * RPI][0]);                   \
  }

  f32x4 acc[WM / 16][WN / 16] = {};

  STAGE(0, 0);
  asm volatile("s_waitcnt vmcnt(0)" ::: "memory");
  __builtin_amdgcn_s_barrier();

  const int NT = K / BK;
  for (int t = 0; t < NT; ++t) {
    const int cur = t & 1;
    if (t + 1 < NT) STAGE(cur ^ 1, (t + 1) * BK);
    bf16x8 af[WM / 16][BK / 32], bfr[WN / 16][BK / 32];
#pragma unroll
    for (int mi = 0; mi < WM / 16; ++mi)
#pragma unroll
      for (int kh = 0; kh < BK / 32; ++kh)
        af[mi][kh] = *reinterpret_cast<const bf16x8*>(
            &As[cur][wr + mi * 16 + row16][((kh * 4 + kgrp) ^ rsw) * 8]);
#pragma unroll
    for (int ni = 0; ni < WN / 16; ++ni)
#pragma unroll
      for (int kh = 0; kh < BK / 32; ++kh)
        bfr[ni][kh] = *reinterpret_cast<const bf16x8*>(
            &Bs[cur][wc + ni * 16 + row16][((kh * 4 + kgrp) ^ rsw) * 8]);
#pragma unroll
    for (int kh = 0; kh < BK / 32; ++kh)
#pragma unroll
      for (int mi = 0; mi < WM / 16; ++mi)
#pragma unroll
        for (int ni = 0; ni < WN / 16; ++ni)
          acc[mi][ni] = __builtin_amdgcn_mfma_f32_16x16x32_bf16(
              af[mi][kh], bfr[ni][kh], acc[mi][ni], 0, 0, 0);
    asm volatile("s_waitcnt vmcnt(0)" ::: "memory");
    __builtin_amdgcn_s_barrier();
  }
#undef STAGE

  if constexpr (OUT_BF16 == 1) {
    unsigned short* Cs = &As[0][0][0];  // >= 128*128 ushorts (free now)
#pragma unroll
    for (int ni = 0; ni < WN / 16; ++ni) {
      const float bv = bias[bn + wc + ni * 16 + row16];
#pragma unroll
      for (int mi = 0; mi < WM / 16; ++mi)
#pragma unroll
        for (int r2 = 0; r2 < 4; ++r2)
          Cs[(wr + mi * 16 + kgrp * 4 + r2) * 128 + wc + ni * 16 + row16] =
              f2bf(acc[mi][ni][r2] + bv);
    }
    __syncthreads();
    unsigned short* Cq = reinterpret_cast<unsigned short*>(Cv);
#pragma unroll
    for (int j = 0; j < 8; ++j) {
      const int row = j * 16 + (tid >> 4);
      const int col = (tid & 15) * 8;
      ushort8 v = *reinterpret_cast<const ushort8*>(&Cs[row * 128 + col]);
      *reinterpret_cast<ushort8*>(&Cq[(size_t)(bm + row) * N + bn + col]) = v;
    }
  } else {
#pragma unroll
    for (int ni = 0; ni < WN / 16; ++ni) {
      const int gcol = bn + wc + ni * 16 + row16;
      const float bv = bias[gcol];
#pragma unroll
      for (int mi = 0; mi < WM / 16; ++mi) {
#pragma unroll
        for (int r2 = 0; r2 < 4; ++r2) {
          const int grow = bm + wr + mi * 16 + kgrp * 4 + r2;
          reinterpret_cast<float*>(Cv)[(size_t)grow * N + gcol] =
              acc[mi][ni][r2] + bv;
        }
      }
    }
  }
}

// ---------------- local (banded) attention, v5: 128 q / block, 8 waves ----------------
// Window: 192 keys (q0-32 .. q0+159) + 16 zero-pad keys, shared by 8 waves.
// Vt row width 106 dwords: 106%32=10 -> 16-row b128 read pattern <=2-way
// bank-aliased (free). LDS 53.8 KB -> 3 blocks/CU = 24 waves/CU (was 16).
__global__ __launch_bounds__(512) void attn_local(
    const unsigned short* __restrict__ qkv, unsigned short* __restrict__ ctx,
    int S) {
  __shared__ unsigned Vt[64][106];           // 27136 B
  __shared__ unsigned short Ps[8][16][104];  // 26624 B

  const int tid = threadIdx.x;
  const int lane = tid & 63;
  const int wid = tid >> 6;  // 0..7

  // bijective XCD-chunked swizzle: nwg = (S/128)*16 = 512
  const int nqb = S >> 7;
  const int nwg = nqb * 16;
  const int orig = blockIdx.y * gridDim.x + blockIdx.x;
  const int cpx = nwg >> 3;
  const int swzb = (orig & 7) * cpx + (orig >> 3);
  const int q0 = (swzb % nqb) * 128;
  const int bh = swzb / nqb;
  const int b = bh >> 3;
  const int h = bh & 7;

  const int row16 = lane & 15;
  const int kgrp = lane >> 4;
  const size_t bS = (size_t)b * S;

  // ---- stage V transposed (packed key pairs): 96 pairs x 4 d-quarters ----
  if (tid < 384) {
    const int k2 = tid >> 2;          // pair 0..95 (window keys 2k2, 2k2+1)
    const int dq = (tid & 3) * 16;
    const int ra = iclamp(q0 - 32 + 2 * k2, 0, S - 1);
    const int rb = iclamp(q0 - 32 + 2 * k2 + 1, 0, S - 1);
    const unsigned short* pa = qkv + (bS + ra) * 1536 + 1024 + h * 64 + dq;
    const unsigned short* pb = qkv + (bS + rb) * 1536 + 1024 + h * 64 + dq;
    ushort8 a0 = reinterpret_cast<const ushort8*>(pa)[0];
    ushort8 a1 = reinterpret_cast<const ushort8*>(pa)[1];
    ushort8 b0 = reinterpret_cast<const ushort8*>(pb)[0];
    ushort8 b1 = reinterpret_cast<const ushort8*>(pb)[1];
#pragma unroll
    for (int d = 0; d < 8; ++d) {
      Vt[dq + d][k2] = (unsigned)a0[d] | ((unsigned)b0[d] << 16);
      Vt[dq + 8 + d][k2] = (unsigned)a1[d] | ((unsigned)b1[d] << 16);
    }
  } else {
    // zero pad dwords 96..103 (window keys 192..207: P=0, V must be finite)
    const int t2 = tid - 384;        // 0..127
    const int zr = t2 & 63;
    const int zc = 96 + ((t2 >> 6) << 2);
#pragma unroll
    for (int j = 0; j < 4; ++j) Vt[zr][zc + j] = 0u;
  }

  // ---- Q fragments (direct from global) ----
  bf16x8 qf0, qf1;
  {
    const unsigned short* qp =
        qkv + (bS + q0 + wid * 16 + row16) * 1536 + h * 64;
    qf0 = *reinterpret_cast<const bf16x8*>(qp + kgrp * 8);
    qf1 = *reinterpret_cast<const bf16x8*>(qp + 32 + kgrp * 8);
  }

  // ---- QK^T: 5 key tiles per wave, K direct from global (clamped) ----
  f32x4 sc[5];
#pragma unroll
  for (int t = 0; t < 5; ++t) {
    const int key = iclamp(q0 - 32 + (wid + t) * 16 + row16, 0, S - 1);
    const unsigned short* kp = qkv + (bS + key) * 1536 + 512 + h * 64;
    bf16x8 kf0 = *reinterpret_cast<const bf16x8*>(kp + kgrp * 8);
    bf16x8 kf1 = *reinterpret_cast<const bf16x8*>(kp + 32 + kgrp * 8);
    f32x4 s = {0.f, 0.f, 0.f, 0.f};
    s = __builtin_amdgcn_mfma_f32_16x16x32_bf16(qf0, kf0, s, 0, 0, 0);
    s = __builtin_amdgcn_mfma_f32_16x16x32_bf16(qf1, kf1, s, 0, 0, 0);
    sc[t] = s;
  }

  // ---- mask + softmax (diff formula is wid-independent) ----
  const int ccol = row16;
  const int crow4 = kgrp * 4;
  float rm[4] = {-INFINITY, -INFINITY, -INFINITY, -INFINITY};
#pragma unroll
  for (int t = 0; t < 5; ++t)
#pragma unroll
    for (int r = 0; r < 4; ++r) {
      const int key_abs = q0 - 32 + (wid + t) * 16 + ccol;
      const int diff = -32 + t * 16 + ccol - crow4 - r;
      float s = sc[t][r] * 0.125f;
      const bool valid =
          (diff >= -32) && (diff <= 32) && (key_abs >= 0) && (key_abs < S);
      s = valid ? s : -INFINITY;
      sc[t][r] = s;
      rm[r] = fmaxf(rm[r], s);
    }
#pragma unroll
  for (int off = 1; off < 16; off <<= 1)
#pragma unroll
    for (int r = 0; r < 4; ++r) rm[r] = fmaxf(rm[r], __shfl_xor(rm[r], off, 64));
  float rs[4] = {0.f, 0.f, 0.f, 0.f};
#pragma unroll
  for (int t = 0; t < 5; ++t)
#pragma unroll
    for (int r = 0; r < 4; ++r) {
      const float p = __expf(sc[t][r] - rm[r]);
      sc[t][r] = p;
      rs[r] += p;
    }
#pragma unroll
  for (int off = 1; off < 16; off <<= 1)
#pragma unroll
    for (int r = 0; r < 4; ++r) rs[r] += __shfl_xor(rs[r], off, 64);

  // ---- P -> LDS (bf16), zero-pad keys 80..95 ----
#pragma unroll
  for (int t = 0; t < 5; ++t)
#pragma unroll
    for (int r = 0; r < 4; ++r)
      Ps[wid][crow4 + r][t * 16 + ccol] = f2bf(sc[t][r]);
#pragma unroll
  for (int j = 0; j < 4; ++j) Ps[wid][row16][80 + kgrp * 4 + j] = 0;

  __syncthreads();  // Vt (cross-wave) + Ps visible

  // ---- PV: ctx[16x64] = P[16x96] * V[96x64]; wave w keys 16w..16w+95 ----
  f32x4 cacc[4] = {};
#pragma unroll
  for (int kc = 0; kc < 3; ++kc) {
    bf16x8 pf = *reinterpret_cast<const bf16x8*>(&Ps[wid][row16][kc * 32 + kgrp * 8]);
#pragma unroll
    for (int ni = 0; ni < 4; ++ni) {
      bf16x8 vf = *reinterpret_cast<const bf16x8*>(
          &Vt[ni * 16 + row16][wid * 8 + kc * 16 + kgrp * 4]);
      cacc[ni] = __builtin_amdgcn_mfma_f32_16x16x32_bf16(pf, vf, cacc[ni], 0, 0, 0);
    }
  }

  // ---- normalize; restage tile in wave-private Ps; coalesced store ----
  float inv[4];
#pragma unroll
  for (int r = 0; r < 4; ++r) inv[r] = 1.0f / rs[r];
#pragma unroll
  for (int ni = 0; ni < 4; ++ni)
#pragma unroll
    for (int r = 0; r < 4; ++r)
      Ps[wid][crow4 + r][ni * 16 + ccol] = f2bf(cacc[ni][r] * inv[r]);
  // wave-private buffer: write->read ordered by lgkmcnt (no barrier needed)
#pragma unroll
  for (int j = 0; j < 2; ++j) {
    ushort8 vv = *reinterpret_cast<const ushort8*>(
        &Ps[wid][j * 8 + (lane >> 3)][(lane & 7) * 8]);
    *reinterpret_cast<ushort8*>(
        &ctx[(bS + q0 + wid * 16 + j * 8 + (lane >> 3)) * 512 + h * 64 +
             (lane & 7) * 8]) = vv;
  }
}

extern "C" void kernel_launch(void* const* d_in, const int* in_sizes, int n_in,
                              void* d_out, int out_size, void* d_ws, size_t ws_size,
                              hipStream_t stream) {
  const float* x = (const float*)d_in[0];
  const float* w_in = (const float*)d_in[1];
  const float* b_in = (const float*)d_in[2];
  const float* w_out = (const float*)d_in[3];
  const float* b_out = (const float*)d_in[4];
  float* out = (float*)d_out;

  const int B = 2, S = 4096, D = 512;
  const int BS = B * S;  // 8192

  char* ws = (char*)d_ws;
  unsigned short* xb = (unsigned short*)(ws + 0);          //  8,388,608
  unsigned short* wbin = (unsigned short*)(ws + 8388608);  //  1,572,864
  unsigned short* wbo = (unsigned short*)(ws + 9961472);   //    524,288
  unsigned short* qkvb = (unsigned short*)(ws + 10485760); // 25,165,824
  unsigned short* ctxb = (unsigned short*)(ws + 35651584); //  8,388,608

  // all fp32->bf16 converts in one launch
  cvt_all<<<2048, 256, 0, stream>>>(x, w_in, w_out, xb, wbin, wbo);

  // QKV projection: [8192,512] x [1536,512]^T -> bf16 [8192,1536]
  gemm_bt<128, 128, 64, 64, 32, 1>
      <<<dim3(12, 64), 256, 0, stream>>>(xb, wbin, b_in, qkvb, BS, 3 * D, D);

  // local attention -> ctx bf16 [8192,512]; 128 q/block, 8 waves
  attn_local<<<dim3(S / 128, 16), 512, 0, stream>>>(qkvb, ctxb, S);

  // out projection: [8192,512] x [512,512]^T -> fp32 d_out
  gemm_bt<64, 128, 32, 64, 64, 0>
      <<<dim3(4, 128), 256, 0, stream>>>(ctxb, wbo, b_out, out, BS, D, D);
}

// Round 16
// 53.293 us; speedup vs baseline: 1.0257x; 1.0257x over previous
//
#include <hip/hip_runtime.h>

typedef __attribute__((ext_vector_type(8))) short bf16x8;
typedef __attribute__((ext_vector_type(8))) unsigned short ushort8;
typedef __attribute__((ext_vector_type(4))) float f32x4;

static __device__ __forceinline__ unsigned short f2bf(float f) {
  union { float f; unsigned u; } v; v.f = f;
  unsigned r = v.u + 0x7FFFu + ((v.u >> 16) & 1u);
  return (unsigned short)(r >> 16);
}
static __device__ __forceinline__ int iclamp(int x, int lo, int hi) {
  return x < lo ? lo : (x > hi ? hi : x);
}
// async global->LDS, 16B per lane; LDS dest = wave-uniform base + lane*16
static __device__ __forceinline__ void gl_lds16(const unsigned short* g,
                                                unsigned short* l) {
  __builtin_amdgcn_global_load_lds(
      (const __attribute__((address_space(1))) void*)g,
      (__attribute__((address_space(3))) void*)l, 16, 0, 0);
}

// ---------------- fused fp32 -> bf16 converts (one launch) ----------------
__global__ void cvt_all(const float* __restrict__ x,
                        const float* __restrict__ w_in,
                        const float* __restrict__ w_out,
                        unsigned short* __restrict__ xb,
                        unsigned short* __restrict__ wbin,
                        unsigned short* __restrict__ wbo) {
  const int NX4 = 1048576, NWI4 = 196608, NWO4 = 65536;  // float4 counts
  const int total = NX4 + NWI4 + NWO4;
  for (int i = blockIdx.x * blockDim.x + threadIdx.x; i < total;
       i += gridDim.x * blockDim.x) {
    const float* src;
    unsigned short* dst;
    int o;
    if (i < NX4) {
      src = x; dst = xb; o = i;
    } else if (i < NX4 + NWI4) {
      src = w_in; dst = wbin; o = i - NX4;
    } else {
      src = w_out; dst = wbo; o = i - NX4 - NWI4;
    }
    float4 v = reinterpret_cast<const float4*>(src)[o];
    ushort4 u;
    u.x = f2bf(v.x); u.y = f2bf(v.y); u.z = f2bf(v.z); u.w = f2bf(v.w);
    reinterpret_cast<ushort4*>(dst)[o] = u;
  }
}

// ------- GEMM: C[M][N] = A[M][K](bf16) * B[N][K](bf16)^T + bias -------
// (r14: 2-phase dbuf, gl_lds w16 pre-swizzled source, post-MFMA drain,
//  BK template; OUT_BF16: vectorized epilogue via C-restage)
template <int BM, int BN, int WM, int WN, int BK, int OUT_BF16>
__global__ __launch_bounds__(256) void gemm_bt(
    const unsigned short* __restrict__ A, const unsigned short* __restrict__ B,
    const float* __restrict__ bias, void* __restrict__ Cv,
    int M, int N, int K) {
  __shared__ unsigned short As[2][BM][BK];
  __shared__ unsigned short Bs[2][BN][BK];
  const int tid = threadIdx.x;
  const int lane = tid & 63;
  const int wid = tid >> 6;

  const int nwg = gridDim.x * gridDim.y;
  const int orig = blockIdx.y * gridDim.x + blockIdx.x;
  const int q = nwg >> 3, r = nwg & 7;
  const int xcd = orig & 7, lid = orig >> 3;
  const int swz = (xcd < r ? xcd * (q + 1) : r * (q + 1) + (xcd - r) * q) + lid;
  const int bm = (swz / gridDim.x) * BM;
  const int bn = (swz % gridDim.x) * BN;

  const int NWC = BN / WN;
  const int wr = (wid / NWC) * WM;
  const int wc = (wid % NWC) * WN;
  const int row16 = lane & 15;
  const int kgrp = lane >> 4;
  const int rsw = (BK == 64) ? (row16 & 7) : (row16 & 3);

  const int RPI = 1024 / (BK * 2);  // rows per gl_lds instr: 8 or 16
  const int lrow = (BK == 64) ? (lane >> 3) : (lane >> 2);
  const int lch = (BK == 64) ? ((lane & 7) ^ (lane >> 3))
                             : ((lane & 3) ^ ((lane >> 2) & 3));
  const int srA = wid * (BM / 4) + lrow;
  const int srB = wid * (BN / 4) + lrow;
  const unsigned short* gA = A + (size_t)(bm + srA) * K + lch * 8;
  const unsigned short* gB = B + (size_t)(bn + srB) * K + lch * 8;
  const size_t KR = (size_t)RPI * K;

#define STAGE(buf, k0)                                                     \
  {                                                                        \
    _Pragma("unroll") for (int j = 0; j < BM / (4 * RPI); ++j)             \
        gl_lds16(gA + j * KR + (k0),                                       \
                 &As[buf][wid * (BM / 4) + j * RPI][0]);                   \
    _Pragma("unroll") for (int j = 0; j < BN / (4 * RPI); ++j)             \
        gl_lds16(gB + j * KR + (k0),                                       \
                 &Bs[buf][wid * (BN / 4) + j * RPI][0]);                   \
  }

  f32x4 acc[WM / 16][WN / 16] = {};

  STAGE(0, 0);
  asm volatile("s_waitcnt vmcnt(0)" ::: "memory");
  __builtin_amdgcn_s_barrier();

  const int NT = K / BK;
  for (int t = 0; t < NT; ++t) {
    const int cur = t & 1;
    if (t + 1 < NT) STAGE(cur ^ 1, (t + 1) * BK);
    bf16x8 af[WM / 16][BK / 32], bfr[WN / 16][BK / 32];
#pragma unroll
    for (int mi = 0; mi < WM / 16; ++mi)
#pragma unroll
      for (int kh = 0; kh < BK / 32; ++kh)
        af[mi][kh] = *reinterpret_cast<const bf16x8*>(
            &As[cur][wr + mi * 16 + row16][((kh * 4 + kgrp) ^ rsw) * 8]);
#pragma unroll
    for (int ni = 0; ni < WN / 16; ++ni)
#pragma unroll
      for (int kh = 0; kh < BK / 32; ++kh)
        bfr[ni][kh] = *reinterpret_cast<const bf16x8*>(
            &Bs[cur][wc + ni * 16 + row16][((kh * 4 + kgrp) ^ rsw) * 8]);
#pragma unroll
    for (int kh = 0; kh < BK / 32; ++kh)
#pragma unroll
      for (int mi = 0; mi < WM / 16; ++mi)
#pragma unroll
        for (int ni = 0; ni < WN / 16; ++ni)
          acc[mi][ni] = __builtin_amdgcn_mfma_f32_16x16x32_bf16(
              af[mi][kh], bfr[ni][kh], acc[mi][ni], 0, 0, 0);
    asm volatile("s_waitcnt vmcnt(0)" ::: "memory");
    __builtin_amdgcn_s_barrier();
  }
#undef STAGE

  if constexpr (OUT_BF16 == 1) {
    unsigned short* Cs = &As[0][0][0];  // >= 128*128 ushorts (free now)
#pragma unroll
    for (int ni = 0; ni < WN / 16; ++ni) {
      const float bv = bias[bn + wc + ni * 16 + row16];
#pragma unroll
      for (int mi = 0; mi < WM / 16; ++mi)
#pragma unroll
        for (int r2 = 0; r2 < 4; ++r2)
          Cs[(wr + mi * 16 + kgrp * 4 + r2) * 128 + wc + ni * 16 + row16] =
              f2bf(acc[mi][ni][r2] + bv);
    }
    __syncthreads();
    unsigned short* Cq = reinterpret_cast<unsigned short*>(Cv);
#pragma unroll
    for (int j = 0; j < 8; ++j) {
      const int row = j * 16 + (tid >> 4);
      const int col = (tid & 15) * 8;
      ushort8 v = *reinterpret_cast<const ushort8*>(&Cs[row * 128 + col]);
      *reinterpret_cast<ushort8*>(&Cq[(size_t)(bm + row) * N + bn + col]) = v;
    }
  } else {
#pragma unroll
    for (int ni = 0; ni < WN / 16; ++ni) {
      const int gcol = bn + wc + ni * 16 + row16;
      const float bv = bias[gcol];
#pragma unroll
      for (int mi = 0; mi < WM / 16; ++mi) {
#pragma unroll
        for (int r2 = 0; r2 < 4; ++r2) {
          const int grow = bm + wr + mi * 16 + kgrp * 4 + r2;
          reinterpret_cast<float*>(Cv)[(size_t)grow * N + gcol] =
              acc[mi][ni][r2] + bv;
        }
      }
    }
  }
}

// ---------------- local (banded) attention, v3 + XCD-chunked grid ----------------
// (r13/r14 best version: 64 q/block, 4 waves, coalesced ctx store)
__global__ __launch_bounds__(256) void attn_local(
    const unsigned short* __restrict__ qkv, unsigned short* __restrict__ ctx,
    int S) {
  __shared__ unsigned Vt[64][76];            // 19456 B
  __shared__ unsigned short Ps[4][16][104];  // 13312 B

  const int tid = threadIdx.x;
  const int lane = tid & 63;
  const int wid = tid >> 6;

  // bijective XCD-chunked swizzle: nwg = (S/64)*16, multiple of 8
  const int nqb = S >> 6;
  const int nwg = nqb * 16;
  const int orig = blockIdx.y * gridDim.x + blockIdx.x;
  const int cpx = nwg >> 3;
  const int swzb = (orig & 7) * cpx + (orig >> 3);
  const int q0 = (swzb % nqb) * 64;
  const int bh = swzb / nqb;
  const int b = bh >> 3;
  const int h = bh & 7;

  const int row16 = lane & 15;
  const int kgrp = lane >> 4;
  const size_t bS = (size_t)b * S;

  // ---- stage V transposed (packed key pairs) ----
  {
    const int k2 = tid >> 2;
    const int dq = (tid & 3) * 16;
    const int ra = iclamp(q0 - 32 + 2 * k2, 0, S - 1);
    const int rb = iclamp(q0 - 32 + 2 * k2 + 1, 0, S - 1);
    const unsigned short* pa = qkv + (bS + ra) * 1536 + 1024 + h * 64 + dq;
    const unsigned short* pb = qkv + (bS + rb) * 1536 + 1024 + h * 64 + dq;
    ushort8 a0 = reinterpret_cast<const ushort8*>(pa)[0];
    ushort8 a1 = reinterpret_cast<const ushort8*>(pa)[1];
    ushort8 b0 = reinterpret_cast<const ushort8*>(pb)[0];
    ushort8 b1 = reinterpret_cast<const ushort8*>(pb)[1];
#pragma unroll
    for (int d = 0; d < 8; ++d) {
      Vt[dq + d][k2] = (unsigned)a0[d] | ((unsigned)b0[d] << 16);
      Vt[dq + 8 + d][k2] = (unsigned)a1[d] | ((unsigned)b1[d] << 16);
    }
    const int zr = tid >> 2;
    const int zc = 64 + (tid & 3) * 2;
    Vt[zr][zc] = 0u;
    Vt[zr][zc + 1] = 0u;
  }

  // ---- Q fragments (direct from global) ----
  bf16x8 qf0, qf1;
  {
    const unsigned short* qp =
        qkv + (bS + q0 + wid * 16 + row16) * 1536 + h * 64;
    qf0 = *reinterpret_cast<const bf16x8*>(qp + kgrp * 8);
    qf1 = *reinterpret_cast<const bf16x8*>(qp + 32 + kgrp * 8);
  }

  // ---- QK^T: 5 key tiles, K direct from global (clamped rows) ----
  f32x4 sc[5];
#pragma unroll
  for (int t = 0; t < 5; ++t) {
    const int key = iclamp(q0 - 32 + (wid + t) * 16 + row16, 0, S - 1);
    const unsigned short* kp = qkv + (bS + key) * 1536 + 512 + h * 64;
    bf16x8 kf0 = *reinterpret_cast<const bf16x8*>(kp + kgrp * 8);
    bf16x8 kf1 = *reinterpret_cast<const bf16x8*>(kp + 32 + kgrp * 8);
    f32x4 s = {0.f, 0.f, 0.f, 0.f};
    s = __builtin_amdgcn_mfma_f32_16x16x32_bf16(qf0, kf0, s, 0, 0, 0);
    s = __builtin_amdgcn_mfma_f32_16x16x32_bf16(qf1, kf1, s, 0, 0, 0);
    sc[t] = s;
  }

  // ---- mask + softmax ----
  const int ccol = row16;
  const int crow4 = kgrp * 4;
  float rm[4] = {-INFINITY, -INFINITY, -INFINITY, -INFINITY};
#pragma unroll
  for (int t = 0; t < 5; ++t)
#pragma unroll
    for (int r = 0; r < 4; ++r) {
      const int key_abs = q0 - 32 + (wid + t) * 16 + ccol;
      const int diff = -32 + t * 16 + ccol - crow4 - r;
      float s = sc[t][r] * 0.125f;
      const bool valid =
          (diff >= -32) && (diff <= 32) && (key_abs >= 0) && (key_abs < S);
      s = valid ? s : -INFINITY;
      sc[t][r] = s;
      rm[r] = fmaxf(rm[r], s);
    }
#pragma unroll
  for (int off = 1; off < 16; off <<= 1)
#pragma unroll
    for (int r = 0; r < 4; ++r) rm[r] = fmaxf(rm[r], __shfl_xor(rm[r], off, 64));
  float rs[4] = {0.f, 0.f, 0.f, 0.f};
#pragma unroll
  for (int t = 0; t < 5; ++t)
#pragma unroll
    for (int r = 0; r < 4; ++r) {
      const float p = __expf(sc[t][r] - rm[r]);
      sc[t][r] = p;
      rs[r] += p;
    }
#pragma unroll
  for (int off = 1; off < 16; off <<= 1)
#pragma unroll
    for (int r = 0; r < 4; ++r) rs[r] += __shfl_xor(rs[r], off, 64);

  // ---- P -> LDS (bf16), zero-pad keys 80..95 ----
#pragma unroll
  for (int t = 0; t < 5; ++t)
#pragma unroll
    for (int r = 0; r < 4; ++r)
      Ps[wid][crow4 + r][t * 16 + ccol] = f2bf(sc[t][r]);
#pragma unroll
  for (int j = 0; j < 4; ++j) Ps[wid][row16][80 + kgrp * 4 + j] = 0;

  __syncthreads();

  // ---- PV: ctx[16x64] = P[16x96] * V[96x64] ----
  f32x4 cacc[4] = {};
#pragma unroll
  for (int kc = 0; kc < 3; ++kc) {
    bf16x8 pf = *reinterpret_cast<const bf16x8*>(&Ps[wid][row16][kc * 32 + kgrp * 8]);
#pragma unroll
    for (int ni = 0; ni < 4; ++ni) {
      bf16x8 vf = *reinterpret_cast<const bf16x8*>(
          &Vt[ni * 16 + row16][wid * 8 + kc * 16 + kgrp * 4]);
      cacc[ni] = __builtin_amdgcn_mfma_f32_16x16x32_bf16(pf, vf, cacc[ni], 0, 0, 0);
    }
  }

  // ---- normalize; restage tile in wave-private Ps; coalesced store ----
  float inv[4];
#pragma unroll
  for (int r = 0; r < 4; ++r) inv[r] = 1.0f / rs[r];
#pragma unroll
  for (int ni = 0; ni < 4; ++ni)
#pragma unroll
    for (int r = 0; r < 4; ++r)
      Ps[wid][crow4 + r][ni * 16 + ccol] = f2bf(cacc[ni][r] * inv[r]);
  // wave-private buffer: write->read ordered by lgkmcnt (no barrier needed)
#pragma unroll
  for (int j = 0; j < 2; ++j) {
    ushort8 vv = *reinterpret_cast<const ushort8*>(
        &Ps[wid][j * 8 + (lane >> 3)][(lane & 7) * 8]);
    *reinterpret_cast<ushort8*>(
        &ctx[(bS + q0 + wid * 16 + j * 8 + (lane >> 3)) * 512 + h * 64 +
             (lane & 7) * 8]) = vv;
  }
}

extern "C" void kernel_launch(void* const* d_in, const int* in_sizes, int n_in,
                              void* d_out, int out_size, void* d_ws, size_t ws_size,
                              hipStream_t stream) {
  const float* x = (const float*)d_in[0];
  const float* w_in = (const float*)d_in[1];
  const float* b_in = (const float*)d_in[2];
  const float* w_out = (const float*)d_in[3];
  const float* b_out = (const float*)d_in[4];
  float* out = (float*)d_out;

  const int B = 2, S = 4096, D = 512;
  const int BS = B * S;  // 8192

  char* ws = (char*)d_ws;
  unsigned short* xb = (unsigned short*)(ws + 0);          //  8,388,608
  unsigned short* wbin = (unsigned short*)(ws + 8388608);  //  1,572,864
  unsigned short* wbo = (unsigned short*)(ws + 9961472);   //    524,288
  unsigned short* qkvb = (unsigned short*)(ws + 10485760); // 25,165,824
  unsigned short* ctxb = (unsigned short*)(ws + 35651584); //  8,388,608

  // all fp32->bf16 converts in one launch
  cvt_all<<<2048, 256, 0, stream>>>(x, w_in, w_out, xb, wbin, wbo);

  // QKV projection: [8192,512] x [1536,512]^T -> bf16 [8192,1536]
  gemm_bt<128, 128, 64, 64, 32, 1>
      <<<dim3(12, 64), 256, 0, stream>>>(xb, wbin, b_in, qkvb, BS, 3 * D, D);

  // local attention -> ctx bf16 [8192,512]; 64 q/block (r13 best config)
  attn_local<<<dim3(S / 64, 16), 256, 0, stream>>>(qkvb, ctxb, S);

  // out projection: [8192,512] x [512,512]^T -> fp32 d_out
  // 64x64 tile -> grid 1024 = 4 blocks/CU, 16 waves/CU (was 2 blocks / 8 waves;
  // B-panel (0.5 MB) re-read x2 is L2-resident, free)
  gemm_bt<64, 64, 32, 32, 64, 0>
      <<<dim3(8, 128), 256, 0, stream>>>(ctxb, wbo, b_out, out, BS, D, D);
}